// Round 5
// baseline (227.242 us; speedup 1.0000x reference)
//
#include <hip/hip_runtime.h>
#include <hip/hip_bf16.h>

// Sparse conv gather->GEMM->scatter for MI355X (gfx950).
//   K0 : cast features f32 -> bf16 table (stored in d_out's tail, overwritten by K3)
//   K2 : ONE launch, two block roles:
//          blocks [0, histBlocks): histogram + slot-table build (8-deep ILP)
//          blocks [histBlocks, ..): per-offset MFMA GEMM, bf16 gather, depth-2
//          pipeline -> vals[pair][64] bf16 (permuted channel layout, 16B stores)
//   K3 : per-row segmented reduce over slot list -> out (single write per row)
// Fallback to a pure-atomic kernel if ws_size is insufficient.

typedef __bf16 bf16x8 __attribute__((ext_vector_type(8)));
typedef __bf16 bf16x4 __attribute__((ext_vector_type(4)));
typedef float f32x4 __attribute__((ext_vector_type(4)));

#define KOFF 27
#define CAP 64
#define WPAD 72  // 64 + 8 pad: wfrag ds_read_b128 16-way conflict -> 2-way (free)

// ---- K0: f32 -> bf16 feature table ----
__global__ __launch_bounds__(256) void k0_cast(const float* __restrict__ f,
                                               __bf16* __restrict__ fb, int nElems) {
  int i = (blockIdx.x * 256 + threadIdx.x) * 8;
  if (i >= nElems) return;
  f32x4 a = *(const f32x4*)(f + i);
  f32x4 b = *(const f32x4*)(f + i + 4);
  bf16x8 v;
#pragma unroll
  for (int j = 0; j < 4; ++j) {
    v[j] = (__bf16)a[j];
    v[j + 4] = (__bf16)b[j];
  }
  *(bf16x8*)(fb + i) = v;
}

// ---- K2: heterogeneous roles: hist blocks + GEMM blocks ----
// GEMM: swapped-operand mfma: D[ch][pair]; lane (g,r) owns pair base+r.
// vals channel layout: c' = g*16 + t*4 + reg  (lane's 16 ch contiguous -> 2x16B stores)
template <int ITER, int HITER>
__global__ __launch_bounds__(256) void k2_combined(
    const __bf16* __restrict__ fb, const float* __restrict__ kern,
    const int* __restrict__ nin, const int* __restrict__ nout,
    int* __restrict__ counts, int* __restrict__ slots,
    __bf16* __restrict__ vals, int Lpairs, int blocksPerK, int histBlocks,
    int cshift) {
  if ((int)blockIdx.x < histBlocks) {
    // ---------------- hist role ----------------
    const int total = KOFF * Lpairs;
    const int tid = blockIdx.x * 256 + threadIdx.x;
    const int stride = histBlocks * 256;
    int rw[HITER];
#pragma unroll
    for (int j = 0; j < HITER; ++j) {
      int p = tid + j * stride;
      rw[j] = (p < total) ? nout[p] : -1;
    }
#pragma unroll
    for (int j = 0; j < HITER; ++j) {
      if (rw[j] >= 0) {
        int rank = atomicAdd(&counts[rw[j] << cshift], 1);
        if (rank < CAP) slots[rw[j] * CAP + rank] = tid + j * stride;
      }
    }
    return;
  }

  // ---------------- GEMM role ----------------
  __shared__ __bf16 ldsBT[64 * WPAD];  // ldsBT[c*WPAD+i] = W[i][c]
  const int b = blockIdx.x - histBlocks;
  const int bk = b / blocksPerK;
  const int chunk = b % blocksPerK;
  const float* kb = kern + bk * 4096;
  for (int idx = threadIdx.x; idx < 4096; idx += 256) {
    int i = idx >> 6, c = idx & 63;
    ldsBT[c * WPAD + i] = (__bf16)kb[idx];
  }
  __syncthreads();

  const int lane = threadIdx.x & 63;
  const int wave = threadIdx.x >> 6;
  const int r = lane & 15, g = lane >> 4;

  // W fragment (A operand): A[m=r][k=g*8+s*32+j]
  bf16x8 wfrag[2][4];
#pragma unroll
  for (int s = 0; s < 2; ++s)
#pragma unroll
    for (int t = 0; t < 4; ++t)
      wfrag[s][t] = *(const bf16x8*)&ldsBT[(t * 16 + r) * WPAD + g * 8 + s * 32];

  const int* ninK = nin + bk * Lpairs;
  const int base0 = chunk * (4 * ITER * 16) + wave * (ITER * 16);
  const int MAXB = Lpairs - 16;  // Lpairs % 16 == 0

  // Clamped tile base: out-of-range tiles recompute the last tile
  // (idempotent duplicate stores of identical values).
#define PB(IT) (((base0 + (IT) * 16) < MAXB) ? (base0 + (IT) * 16) : MAXB)

  // Pipeline: indices depth-3, features depth-2 (4 gather loads in flight).
  int rowA = ninK[PB(0) + r];
  int rowB = ninK[PB(1) + r];
  int rowC = ninK[PB(2) + r];
  bf16x8 aA0 = *(const bf16x8*)&fb[(size_t)rowA * 64 + g * 8];
  bf16x8 aA1 = *(const bf16x8*)&fb[(size_t)rowA * 64 + 32 + g * 8];
  bf16x8 aB0 = *(const bf16x8*)&fb[(size_t)rowB * 64 + g * 8];
  bf16x8 aB1 = *(const bf16x8*)&fb[(size_t)rowB * 64 + 32 + g * 8];

#pragma unroll
  for (int it = 0; it < ITER; ++it) {
    bf16x8 aC0, aC1;
    int rowN = 0;
    if (it + 2 < ITER) {
      aC0 = *(const bf16x8*)&fb[(size_t)rowC * 64 + g * 8];
      aC1 = *(const bf16x8*)&fb[(size_t)rowC * 64 + 32 + g * 8];
    }
    if (it + 3 < ITER) rowN = ninK[PB(it + 3) + r];

    f32x4 acc[4] = {f32x4{0.f, 0.f, 0.f, 0.f}, f32x4{0.f, 0.f, 0.f, 0.f},
                    f32x4{0.f, 0.f, 0.f, 0.f}, f32x4{0.f, 0.f, 0.f, 0.f}};
#pragma unroll
    for (int t = 0; t < 4; ++t) {
      acc[t] = __builtin_amdgcn_mfma_f32_16x16x32_bf16(wfrag[0][t], aA0, acc[t], 0, 0, 0);
      acc[t] = __builtin_amdgcn_mfma_f32_16x16x32_bf16(wfrag[1][t], aA1, acc[t], 0, 0, 0);
    }

    // Store: lane's channels c' = g*16 + t*4 + reg -> two contiguous 16B stores.
    __bf16* vp = vals + ((size_t)bk * Lpairs + PB(it) + r) * 64 + g * 16;
    bf16x8 v0, v1;
#pragma unroll
    for (int reg = 0; reg < 4; ++reg) {
      v0[reg] = (__bf16)acc[0][reg];
      v0[reg + 4] = (__bf16)acc[1][reg];
      v1[reg] = (__bf16)acc[2][reg];
      v1[reg + 4] = (__bf16)acc[3][reg];
    }
    *(bf16x8*)vp = v0;
    *(bf16x8*)(vp + 8) = v1;

    // rotate pipeline
    aA0 = aB0; aA1 = aB1;
    aB0 = aC0; aB1 = aC1;
    rowC = rowN;
  }
#undef PB
}

// ---- K3: per-row segmented reduce, 4-deep ILP, inverse channel perm ----
__global__ __launch_bounds__(256) void k3_reduce(const __bf16* __restrict__ vals,
                                                 const int* __restrict__ counts,
                                                 const int* __restrict__ slots,
                                                 float* __restrict__ out, int Nrows,
                                                 int cshift) {
  const int wid = (blockIdx.x * 256 + threadIdx.x) >> 6;
  const int lane = threadIdx.x & 63;
  if (wid >= Nrows) return;
  // out channel c=lane lives at vals offset c' = ((c>>2)&3)*16 + (c>>4)*4 + (c&3)
  const int cp = ((lane >> 2) & 3) * 16 + (lane >> 4) * 4 + (lane & 3);
  int cnt = counts[wid << cshift];
  cnt = cnt > CAP ? CAP : cnt;
  int myslot = (lane < cnt) ? slots[wid * CAP + lane] : 0;
  float acc = 0.f;
  int j = 0;
  for (; j + 3 < cnt; j += 4) {
    int s0 = __shfl(myslot, j);
    int s1 = __shfl(myslot, j + 1);
    int s2 = __shfl(myslot, j + 2);
    int s3 = __shfl(myslot, j + 3);
    float v0 = (float)vals[(size_t)s0 * 64 + cp];
    float v1 = (float)vals[(size_t)s1 * 64 + cp];
    float v2 = (float)vals[(size_t)s2 * 64 + cp];
    float v3 = (float)vals[(size_t)s3 * 64 + cp];
    acc += v0; acc += v1; acc += v2; acc += v3;
  }
  for (; j < cnt; ++j) {
    int s0 = __shfl(myslot, j);
    acc += (float)vals[(size_t)s0 * 64 + cp];
  }
  out[(size_t)wid * 64 + lane] = acc;
}

// ---- Fallback: atomic kernel (used only if ws too small) ----
template <int ITER>
__global__ __launch_bounds__(256) void spconv_atomic_kernel(
    const float* __restrict__ feat, const float* __restrict__ kern,
    const int* __restrict__ nin, const int* __restrict__ nout,
    float* __restrict__ out, int Lpairs, int blocksPerK) {
  __shared__ __bf16 ldsBT[64 * WPAD];
  const int bk = blockIdx.x / blocksPerK;
  const int chunk = blockIdx.x % blocksPerK;
  const float* kb = kern + bk * 4096;
  for (int idx = threadIdx.x; idx < 4096; idx += 256) {
    int i = idx >> 6, c = idx & 63;
    ldsBT[c * WPAD + i] = (__bf16)kb[idx];
  }
  __syncthreads();
  const int lane = threadIdx.x & 63;
  const int wave = threadIdx.x >> 6;
  const int r = lane & 15, g = lane >> 4;
  bf16x8 bfrag[2][4];
#pragma unroll
  for (int s = 0; s < 2; ++s)
#pragma unroll
    for (int t = 0; t < 4; ++t)
      bfrag[s][t] = *(const bf16x8*)&ldsBT[(t * 16 + r) * WPAD + g * 8 + s * 32];
  const int* ninK = nin + bk * Lpairs;
  const int* noutK = nout + bk * Lpairs;
  const int base0 = chunk * (4 * ITER * 16) + wave * (ITER * 16);
  for (int it = 0; it < ITER; ++it) {
    const int base = base0 + it * 16;
    if (base >= Lpairs) break;
    const int arow = ninK[base + r];
    const float* ap = feat + (size_t)arow * 64 + g * 8;
    f32x4 f0 = *(const f32x4*)(ap);
    f32x4 f1 = *(const f32x4*)(ap + 4);
    f32x4 f2 = *(const f32x4*)(ap + 32);
    f32x4 f3 = *(const f32x4*)(ap + 36);
    bf16x8 a0, a1;
#pragma unroll
    for (int j = 0; j < 4; ++j) {
      a0[j] = (__bf16)f0[j];
      a0[j + 4] = (__bf16)f1[j];
      a1[j] = (__bf16)f2[j];
      a1[j + 4] = (__bf16)f3[j];
    }
    f32x4 acc[4] = {f32x4{0.f, 0.f, 0.f, 0.f}, f32x4{0.f, 0.f, 0.f, 0.f},
                    f32x4{0.f, 0.f, 0.f, 0.f}, f32x4{0.f, 0.f, 0.f, 0.f}};
#pragma unroll
    for (int t = 0; t < 4; ++t) {
      acc[t] = __builtin_amdgcn_mfma_f32_16x16x32_bf16(a0, bfrag[0][t], acc[t], 0, 0, 0);
      acc[t] = __builtin_amdgcn_mfma_f32_16x16x32_bf16(a1, bfrag[1][t], acc[t], 0, 0, 0);
    }
    int orow[4];
#pragma unroll
    for (int reg = 0; reg < 4; ++reg) orow[reg] = noutK[base + g * 4 + reg];
#pragma unroll
    for (int t = 0; t < 4; ++t)
#pragma unroll
      for (int reg = 0; reg < 4; ++reg)
        atomicAdd(out + (size_t)orow[reg] * 64 + t * 16 + r, acc[t][reg]);
  }
}

extern "C" void kernel_launch(void* const* d_in, const int* in_sizes, int n_in,
                              void* d_out, int out_size, void* d_ws, size_t ws_size,
                              hipStream_t stream) {
  const float* feat = (const float*)d_in[0];
  const float* kern = (const float*)d_in[1];
  const int* nin = (const int*)d_in[2];
  const int* nout = (const int*)d_in[3];
  float* out = (float*)d_out;

  const int total = in_sizes[2];        // 27*L pairs
  const int Lpairs = total / KOFF;      // 50000
  const int Nrows = out_size / 64;      // 100000

  constexpr int ITER = 8;
  constexpr int HITER = 8;
  const int pairsPerBlock = 4 * ITER * 16;  // 512
  const int blocksPerK = (Lpairs + pairsPerBlock - 1) / pairsPerBlock;
  const int histBlocks = (total + 256 * HITER - 1) / (256 * HITER);

  // ws layout: counts (padded by 1<<cshift ints), slots, vals.
  // bf16 feature table lives in d_out's storage (fully overwritten by K3).
  int cshift = -1;
  size_t countsBytes = 0, slotsOff = 0, valsOff = 0;
  for (int cs = 4; cs >= 0; cs -= 2) {
    size_t cb = ((size_t)Nrows << cs) * 4;
    size_t so = (cb + 255) & ~(size_t)255;
    size_t vo = ((so + (size_t)Nrows * CAP * 4) + 255) & ~(size_t)255;
    size_t needed = vo + (size_t)total * 64 * 2;
    if (ws_size >= needed) { cshift = cs; countsBytes = cb; slotsOff = so; valsOff = vo; break; }
  }

  if (cshift >= 0) {
    int* counts = (int*)d_ws;
    int* slots = (int*)((char*)d_ws + slotsOff);
    __bf16* vals = (__bf16*)((char*)d_ws + valsOff);
    __bf16* fb = (__bf16*)d_out;  // 12.8 MB scratch inside 25.6 MB out buffer

    hipMemsetAsync(counts, 0, countsBytes, stream);
    k0_cast<<<(Nrows * 64 / 8 + 255) / 256, 256, 0, stream>>>(feat, fb, Nrows * 64);
    k2_combined<ITER, HITER><<<histBlocks + KOFF * blocksPerK, 256, 0, stream>>>(
        fb, kern, nin, nout, counts, slots, vals, Lpairs, blocksPerK, histBlocks,
        cshift);
    k3_reduce<<<(Nrows * 64 + 255) / 256, 256, 0, stream>>>(vals, counts, slots,
                                                            out, Nrows, cshift);
  } else {
    hipMemsetAsync(d_out, 0, (size_t)out_size * sizeof(float), stream);
    spconv_atomic_kernel<ITER><<<KOFF * blocksPerK, 256, 0, stream>>>(
        feat, kern, nin, nout, out, Lpairs, blocksPerK);
  }
}

// Round 6
// 168.264 us; speedup vs baseline: 1.3505x; 1.3505x over previous
//
#include <hip/hip_runtime.h>
#include <hip/hip_bf16.h>

// Sparse conv gather->GEMM->scatter for MI355X (gfx950).
//   K0 : cast features f32 -> bf16 table (stored in d_out, overwritten by K3)
//   K2 : per-offset MFMA GEMM, bf16 gather, depth-4 register pipeline
//        -> vals[pair][64] bf16 (permuted channel layout, 2x16B stores/lane)
//        + fused histogram/slot-table at wave end (spread over 4 lane-groups)
//   K3 : per-row segmented reduce over slot list -> out (single write per row)
// Fallback to a pure-atomic kernel if ws_size is insufficient.

typedef __bf16 bf16x8 __attribute__((ext_vector_type(8)));
typedef __bf16 bf16x4 __attribute__((ext_vector_type(4)));
typedef float f32x4 __attribute__((ext_vector_type(4)));

#define KOFF 27
#define CAP 64
#define WPAD 72  // 64 + 8 pad: wfrag ds_read_b128 16-way conflict -> 2-way (free)

// ---- K0: f32 -> bf16 feature table ----
__global__ __launch_bounds__(256) void k0_cast(const float* __restrict__ f,
                                               __bf16* __restrict__ fb, int nElems) {
  int i = (blockIdx.x * 256 + threadIdx.x) * 8;
  if (i >= nElems) return;
  f32x4 a = *(const f32x4*)(f + i);
  f32x4 b = *(const f32x4*)(f + i + 4);
  bf16x8 v;
#pragma unroll
  for (int j = 0; j < 4; ++j) {
    v[j] = (__bf16)a[j];
    v[j + 4] = (__bf16)b[j];
  }
  *(bf16x8*)(fb + i) = v;
}

// ---- K2: GEMM (depth-4 pipeline) + wave-end hist ----
// Swapped-operand mfma: D[ch][pair]; lane (g,r) owns pair base+r.
// vals channel layout: c' = g*16 + t*4 + reg (lane's 16 ch contiguous).
template <int ITER>
__global__ __launch_bounds__(256) void k2_gemm_hist(
    const __bf16* __restrict__ fb, const float* __restrict__ kern,
    const int* __restrict__ nin, const int* __restrict__ nout,
    int* __restrict__ counts, int* __restrict__ slots,
    __bf16* __restrict__ vals, int Lpairs, int blocksPerK, int cshift) {
  __shared__ __bf16 ldsBT[64 * WPAD];  // ldsBT[c*WPAD+i] = W[i][c]
  const int bk = blockIdx.x / blocksPerK;
  const int chunk = blockIdx.x % blocksPerK;
  const float* kb = kern + bk * 4096;
  for (int idx = threadIdx.x; idx < 4096; idx += 256) {
    int i = idx >> 6, c = idx & 63;
    ldsBT[c * WPAD + i] = (__bf16)kb[idx];
  }
  __syncthreads();

  const int lane = threadIdx.x & 63;
  const int wave = threadIdx.x >> 6;
  const int r = lane & 15, g = lane >> 4;

  // W fragment (A operand): A[m=r][k=g*8+s*32+j]
  bf16x8 wfrag[2][4];
#pragma unroll
  for (int s = 0; s < 2; ++s)
#pragma unroll
    for (int t = 0; t < 4; ++t)
      wfrag[s][t] = *(const bf16x8*)&ldsBT[(t * 16 + r) * WPAD + g * 8 + s * 32];

  const int* ninK = nin + bk * Lpairs;
  const int* noutK = nout + bk * Lpairs;
  const int base0 = chunk * (4 * ITER * 16) + wave * (ITER * 16);
  const int MAXB = Lpairs - 16;  // Lpairs % 16 == 0

  // Clamped tile base: out-of-range tiles recompute the last tile
  // (idempotent duplicate stores of identical values).
#define PB(IT) (((base0 + (IT) * 16) < MAXB) ? (base0 + (IT) * 16) : MAXB)

  // Hist rows: lane-group g owns tiles it = 2g, 2g+1 (2 short atomic chains/lane).
  const int hit0 = 2 * g, hit1 = 2 * g + 1;
  const int h0 = noutK[PB(hit0) + r];
  const int h1 = noutK[PB(hit1) + r];

  // All 8 tile-indices up front (8 independent 4B loads).
  int rows[ITER];
#pragma unroll
  for (int it = 0; it < ITER; ++it) rows[it] = ninK[PB(it) + r];

  // Feature pipeline: depth 4 (3 buffered + 1 issuing) -> 8 loads in flight.
  bf16x8 A0[4], A1[4];
#pragma unroll
  for (int d = 0; d < 3; ++d) {
    const __bf16* ap = fb + (size_t)rows[d] * 64 + g * 8;
    A0[d] = *(const bf16x8*)(ap);
    A1[d] = *(const bf16x8*)(ap + 32);
  }

#pragma unroll
  for (int it = 0; it < ITER; ++it) {
    if (it + 3 < ITER) {
      const __bf16* ap = fb + (size_t)rows[it + 3] * 64 + g * 8;
      A0[(it + 3) & 3] = *(const bf16x8*)(ap);
      A1[(it + 3) & 3] = *(const bf16x8*)(ap + 32);
    }

    f32x4 acc[4] = {f32x4{0.f, 0.f, 0.f, 0.f}, f32x4{0.f, 0.f, 0.f, 0.f},
                    f32x4{0.f, 0.f, 0.f, 0.f}, f32x4{0.f, 0.f, 0.f, 0.f}};
#pragma unroll
    for (int t = 0; t < 4; ++t) {
      acc[t] = __builtin_amdgcn_mfma_f32_16x16x32_bf16(wfrag[0][t], A0[it & 3], acc[t], 0, 0, 0);
      acc[t] = __builtin_amdgcn_mfma_f32_16x16x32_bf16(wfrag[1][t], A1[it & 3], acc[t], 0, 0, 0);
    }

    // Store: lane's channels c' = g*16 + t*4 + reg -> two contiguous 16B stores.
    __bf16* vp = vals + ((size_t)bk * Lpairs + PB(it) + r) * 64 + g * 16;
    bf16x8 v0, v1;
#pragma unroll
    for (int reg = 0; reg < 4; ++reg) {
      v0[reg] = (__bf16)acc[0][reg];
      v0[reg + 4] = (__bf16)acc[1][reg];
      v1[reg] = (__bf16)acc[2][reg];
      v1[reg + 4] = (__bf16)acc[3][reg];
    }
    *(bf16x8*)vp = v0;
    *(bf16x8*)(vp + 8) = v1;
  }

  // Fused histogram at wave end; exactly-once predicate uses unclamped base.
  if (base0 + hit0 * 16 < Lpairs) {
    int rank = atomicAdd(&counts[h0 << cshift], 1);
    if (rank < CAP) slots[h0 * CAP + rank] = bk * Lpairs + base0 + hit0 * 16 + r;
  }
  if (base0 + hit1 * 16 < Lpairs) {
    int rank = atomicAdd(&counts[h1 << cshift], 1);
    if (rank < CAP) slots[h1 * CAP + rank] = bk * Lpairs + base0 + hit1 * 16 + r;
  }
#undef PB
}

// ---- K3: per-row segmented reduce, 4-deep ILP, inverse channel perm ----
__global__ __launch_bounds__(256) void k3_reduce(const __bf16* __restrict__ vals,
                                                 const int* __restrict__ counts,
                                                 const int* __restrict__ slots,
                                                 float* __restrict__ out, int Nrows,
                                                 int cshift) {
  const int wid = (blockIdx.x * 256 + threadIdx.x) >> 6;
  const int lane = threadIdx.x & 63;
  if (wid >= Nrows) return;
  // out channel c=lane lives at vals offset c' = ((c>>2)&3)*16 + (c>>4)*4 + (c&3)
  const int cp = ((lane >> 2) & 3) * 16 + (lane >> 4) * 4 + (lane & 3);
  int cnt = counts[wid << cshift];
  cnt = cnt > CAP ? CAP : cnt;
  int myslot = (lane < cnt) ? slots[wid * CAP + lane] : 0;
  float acc = 0.f;
  int j = 0;
  for (; j + 3 < cnt; j += 4) {
    int s0 = __shfl(myslot, j);
    int s1 = __shfl(myslot, j + 1);
    int s2 = __shfl(myslot, j + 2);
    int s3 = __shfl(myslot, j + 3);
    float v0 = (float)vals[(size_t)s0 * 64 + cp];
    float v1 = (float)vals[(size_t)s1 * 64 + cp];
    float v2 = (float)vals[(size_t)s2 * 64 + cp];
    float v3 = (float)vals[(size_t)s3 * 64 + cp];
    acc += v0; acc += v1; acc += v2; acc += v3;
  }
  for (; j < cnt; ++j) {
    int s0 = __shfl(myslot, j);
    acc += (float)vals[(size_t)s0 * 64 + cp];
  }
  out[(size_t)wid * 64 + lane] = acc;
}

// ---- Fallback: atomic kernel (used only if ws too small) ----
template <int ITER>
__global__ __launch_bounds__(256) void spconv_atomic_kernel(
    const float* __restrict__ feat, const float* __restrict__ kern,
    const int* __restrict__ nin, const int* __restrict__ nout,
    float* __restrict__ out, int Lpairs, int blocksPerK) {
  __shared__ __bf16 ldsBT[64 * WPAD];
  const int bk = blockIdx.x / blocksPerK;
  const int chunk = blockIdx.x % blocksPerK;
  const float* kb = kern + bk * 4096;
  for (int idx = threadIdx.x; idx < 4096; idx += 256) {
    int i = idx >> 6, c = idx & 63;
    ldsBT[c * WPAD + i] = (__bf16)kb[idx];
  }
  __syncthreads();
  const int lane = threadIdx.x & 63;
  const int wave = threadIdx.x >> 6;
  const int r = lane & 15, g = lane >> 4;
  bf16x8 bfrag[2][4];
#pragma unroll
  for (int s = 0; s < 2; ++s)
#pragma unroll
    for (int t = 0; t < 4; ++t)
      bfrag[s][t] = *(const bf16x8*)&ldsBT[(t * 16 + r) * WPAD + g * 8 + s * 32];
  const int* ninK = nin + bk * Lpairs;
  const int* noutK = nout + bk * Lpairs;
  const int base0 = chunk * (4 * ITER * 16) + wave * (ITER * 16);
  for (int it = 0; it < ITER; ++it) {
    const int base = base0 + it * 16;
    if (base >= Lpairs) break;
    const int arow = ninK[base + r];
    const float* ap = feat + (size_t)arow * 64 + g * 8;
    f32x4 f0 = *(const f32x4*)(ap);
    f32x4 f1 = *(const f32x4*)(ap + 4);
    f32x4 f2 = *(const f32x4*)(ap + 32);
    f32x4 f3 = *(const f32x4*)(ap + 36);
    bf16x8 a0, a1;
#pragma unroll
    for (int j = 0; j < 4; ++j) {
      a0[j] = (__bf16)f0[j];
      a0[j + 4] = (__bf16)f1[j];
      a1[j] = (__bf16)f2[j];
      a1[j + 4] = (__bf16)f3[j];
    }
    f32x4 acc[4] = {f32x4{0.f, 0.f, 0.f, 0.f}, f32x4{0.f, 0.f, 0.f, 0.f},
                    f32x4{0.f, 0.f, 0.f, 0.f}, f32x4{0.f, 0.f, 0.f, 0.f}};
#pragma unroll
    for (int t = 0; t < 4; ++t) {
      acc[t] = __builtin_amdgcn_mfma_f32_16x16x32_bf16(a0, bfrag[0][t], acc[t], 0, 0, 0);
      acc[t] = __builtin_amdgcn_mfma_f32_16x16x32_bf16(a1, bfrag[1][t], acc[t], 0, 0, 0);
    }
    int orow[4];
#pragma unroll
    for (int reg = 0; reg < 4; ++reg) orow[reg] = noutK[base + g * 4 + reg];
#pragma unroll
    for (int t = 0; t < 4; ++t)
#pragma unroll
      for (int reg = 0; reg < 4; ++reg)
        atomicAdd(out + (size_t)orow[reg] * 64 + t * 16 + r, acc[t][reg]);
  }
}

extern "C" void kernel_launch(void* const* d_in, const int* in_sizes, int n_in,
                              void* d_out, int out_size, void* d_ws, size_t ws_size,
                              hipStream_t stream) {
  const float* feat = (const float*)d_in[0];
  const float* kern = (const float*)d_in[1];
  const int* nin = (const int*)d_in[2];
  const int* nout = (const int*)d_in[3];
  float* out = (float*)d_out;

  const int total = in_sizes[2];        // 27*L pairs
  const int Lpairs = total / KOFF;      // 50000
  const int Nrows = out_size / 64;      // 100000

  constexpr int ITER = 8;
  const int pairsPerBlock = 4 * ITER * 16;  // 512
  const int blocksPerK = (Lpairs + pairsPerBlock - 1) / pairsPerBlock;

  // ws layout: counts (padded by 1<<cshift ints), slots, vals.
  int cshift = -1;
  size_t countsBytes = 0, slotsOff = 0, valsOff = 0;
  for (int cs = 4; cs >= 0; cs -= 2) {
    size_t cb = ((size_t)Nrows << cs) * 4;
    size_t so = (cb + 255) & ~(size_t)255;
    size_t vo = ((so + (size_t)Nrows * CAP * 4) + 255) & ~(size_t)255;
    size_t needed = vo + (size_t)total * 64 * 2;
    if (ws_size >= needed) { cshift = cs; countsBytes = cb; slotsOff = so; valsOff = vo; break; }
  }

  if (cshift >= 0) {
    int* counts = (int*)d_ws;
    int* slots = (int*)((char*)d_ws + slotsOff);
    __bf16* vals = (__bf16*)((char*)d_ws + valsOff);
    __bf16* fb = (__bf16*)d_out;  // 12.8 MB scratch inside 25.6 MB out buffer

    hipMemsetAsync(counts, 0, countsBytes, stream);
    k0_cast<<<(Nrows * 64 / 8 + 255) / 256, 256, 0, stream>>>(feat, fb, Nrows * 64);
    k2_gemm_hist<ITER><<<KOFF * blocksPerK, 256, 0, stream>>>(
        fb, kern, nin, nout, counts, slots, vals, Lpairs, blocksPerK, cshift);
    k3_reduce<<<(Nrows * 64 + 255) / 256, 256, 0, stream>>>(vals, counts, slots,
                                                            out, Nrows, cshift);
  } else {
    hipMemsetAsync(d_out, 0, (size_t)out_size * sizeof(float), stream);
    spconv_atomic_kernel<ITER><<<KOFF * blocksPerK, 256, 0, stream>>>(
        feat, kern, nin, nout, out, Lpairs, blocksPerK);
  }
}

// Round 7
// 160.431 us; speedup vs baseline: 1.4164x; 1.0488x over previous
//
#include <hip/hip_runtime.h>
#include <hip/hip_bf16.h>

// Sparse conv gather->GEMM->scatter for MI355X (gfx950), atomic-light design:
//   kA : 27 rank-blocks (per-k LDS nibble-counter rank assignment -> sparse slot
//        table [row][27][4] uint16) + 3125 cast-blocks (f32 -> bf16 features)
//   k2 : PURE per-offset MFMA GEMM, bf16 gather, depth-4 register pipeline
//        -> vals[pair][64] bf16 (permuted channel layout, 2x16B stores/lane)
//   k3 : per-row slot-scan + compaction + 4-deep segmented reduce -> out
//   k4 : tiny fixup applying rank-overflow pairs (~500) with f32 atomics
// Fallback to a pure-atomic kernel for exotic shapes / tiny ws.

typedef __bf16 bf16x8 __attribute__((ext_vector_type(8)));
typedef float f32x4 __attribute__((ext_vector_type(4)));

#define KOFF 27
#define SLOTK 4                 // slots per (row,k) cell
#define NSLOT (KOFF * SLOTK)    // 108 entries per row
#define OVFCAP 8192             // overflow list capacity (E[ovf] ~ 505)
#define WPAD 72                 // LDS pad for W tile
#define NIBWORDS 12800          // 12800 words * 8 nibbles = 102400 rows max

// ---- kA: rank-builder (blocks 0..26) + f32->bf16 cast (rest) ----
__global__ __launch_bounds__(256) void kA_rank_cast(
    const float* __restrict__ feat, const int* __restrict__ nout,
    __bf16* __restrict__ fb, unsigned short* __restrict__ slots,
    int2* __restrict__ ovf, int* __restrict__ ovfcnt, int Lpairs, int nElems) {
  __shared__ unsigned int nib[NIBWORDS];
  if ((int)blockIdx.x < KOFF) {
    const int k = blockIdx.x;
    const int tid = threadIdx.x;
    for (int i = tid; i < NIBWORDS; i += 256) nib[i] = 0u;
    __syncthreads();
    const int* nk = nout + k * Lpairs;
    for (int base = 0; base < Lpairs; base += 2048) {
      int l[8], row[8];
#pragma unroll
      for (int j = 0; j < 8; ++j) {
        l[j] = base + j * 256 + tid;
        row[j] = (l[j] < Lpairs) ? nk[l[j]] : -1;
      }
#pragma unroll
      for (int j = 0; j < 8; ++j) {
        if (row[j] >= 0) {
          unsigned int sh = ((unsigned)row[j] & 7u) * 4u;
          unsigned int old = atomicAdd(&nib[row[j] >> 3], 1u << sh);
          int rank = (old >> sh) & 15;
          if (rank < SLOTK) {
            slots[(size_t)row[j] * NSLOT + k * SLOTK + rank] =
                (unsigned short)l[j];
          } else {
            int idx = atomicAdd(ovfcnt, 1);
            if (idx < OVFCAP) ovf[idx] = make_int2(row[j], k * Lpairs + l[j]);
          }
        }
      }
    }
  } else {
    int i = ((blockIdx.x - KOFF) * 256 + threadIdx.x) * 8;
    if (i < nElems) {
      f32x4 a = *(const f32x4*)(feat + i);
      f32x4 b = *(const f32x4*)(feat + i + 4);
      bf16x8 v;
#pragma unroll
      for (int j = 0; j < 4; ++j) {
        v[j] = (__bf16)a[j];
        v[j + 4] = (__bf16)b[j];
      }
      *(bf16x8*)(fb + i) = v;
    }
  }
}

// ---- k2: PURE GEMM (depth-4 pipeline) ----
// Swapped-operand mfma: D[ch][pair]; lane (g,r) owns pair base+r.
// vals channel layout: c' = g*16 + t*4 + reg (lane's 16 ch contiguous).
template <int ITER>
__global__ __launch_bounds__(256) void k2_gemm(
    const __bf16* __restrict__ fb, const float* __restrict__ kern,
    const int* __restrict__ nin, __bf16* __restrict__ vals, int Lpairs,
    int blocksPerK) {
  __shared__ __bf16 ldsBT[64 * WPAD];  // ldsBT[c*WPAD+i] = W[i][c]
  const int bk = blockIdx.x / blocksPerK;
  const int chunk = blockIdx.x % blocksPerK;
  const float* kb = kern + bk * 4096;
  for (int idx = threadIdx.x; idx < 4096; idx += 256) {
    int i = idx >> 6, c = idx & 63;
    ldsBT[c * WPAD + i] = (__bf16)kb[idx];
  }
  __syncthreads();

  const int lane = threadIdx.x & 63;
  const int wave = threadIdx.x >> 6;
  const int r = lane & 15, g = lane >> 4;

  bf16x8 wfrag[2][4];
#pragma unroll
  for (int s = 0; s < 2; ++s)
#pragma unroll
    for (int t = 0; t < 4; ++t)
      wfrag[s][t] = *(const bf16x8*)&ldsBT[(t * 16 + r) * WPAD + g * 8 + s * 32];

  const int* ninK = nin + bk * Lpairs;
  const int base0 = chunk * (4 * ITER * 16) + wave * (ITER * 16);
  const int MAXB = Lpairs - 16;  // Lpairs % 16 == 0

  // Clamped tile base: out-of-range tiles recompute the last tile
  // (idempotent duplicate stores of identical values).
#define PB(IT) (((base0 + (IT) * 16) < MAXB) ? (base0 + (IT) * 16) : MAXB)

  int rows[ITER];
#pragma unroll
  for (int it = 0; it < ITER; ++it) rows[it] = ninK[PB(it) + r];

  // Feature pipeline: depth 4 (3 buffered + 1 issuing) -> 8 loads in flight.
  bf16x8 A0[4], A1[4];
#pragma unroll
  for (int d = 0; d < 3; ++d) {
    const __bf16* ap = fb + (size_t)rows[d] * 64 + g * 8;
    A0[d] = *(const bf16x8*)(ap);
    A1[d] = *(const bf16x8*)(ap + 32);
  }

#pragma unroll
  for (int it = 0; it < ITER; ++it) {
    if (it + 3 < ITER) {
      const __bf16* ap = fb + (size_t)rows[it + 3] * 64 + g * 8;
      A0[(it + 3) & 3] = *(const bf16x8*)(ap);
      A1[(it + 3) & 3] = *(const bf16x8*)(ap + 32);
    }

    f32x4 acc[4] = {f32x4{0.f, 0.f, 0.f, 0.f}, f32x4{0.f, 0.f, 0.f, 0.f},
                    f32x4{0.f, 0.f, 0.f, 0.f}, f32x4{0.f, 0.f, 0.f, 0.f}};
#pragma unroll
    for (int t = 0; t < 4; ++t) {
      acc[t] = __builtin_amdgcn_mfma_f32_16x16x32_bf16(wfrag[0][t], A0[it & 3], acc[t], 0, 0, 0);
      acc[t] = __builtin_amdgcn_mfma_f32_16x16x32_bf16(wfrag[1][t], A1[it & 3], acc[t], 0, 0, 0);
    }

    __bf16* vp = vals + ((size_t)bk * Lpairs + PB(it) + r) * 64 + g * 16;
    bf16x8 v0, v1;
#pragma unroll
    for (int reg = 0; reg < 4; ++reg) {
      v0[reg] = (__bf16)acc[0][reg];
      v0[reg + 4] = (__bf16)acc[1][reg];
      v1[reg] = (__bf16)acc[2][reg];
      v1[reg + 4] = (__bf16)acc[3][reg];
    }
    *(bf16x8*)vp = v0;
    *(bf16x8*)(vp + 8) = v1;
  }
#undef PB
}

// ---- k3: slot-scan + compact + 4-deep reduce ----
__global__ __launch_bounds__(256) void k3_reduce(
    const __bf16* __restrict__ vals, const unsigned int* __restrict__ slots32,
    float* __restrict__ out, int Nrows, int Lpairs) {
  __shared__ int list[4][64];
  const int w = threadIdx.x >> 6;
  const int lane = threadIdx.x & 63;
  int row = blockIdx.x * 4 + w;
  if (row >= Nrows) row = Nrows - 1;  // duplicate-process last row (benign)

  // 108 uint16 entries = 54 dwords; lane < 54 loads one dword (2 entries).
  unsigned int wv = 0xFFFFFFFFu;
  if (lane < NSLOT / 2) wv = slots32[(size_t)row * (NSLOT / 2) + lane];
  const int e0 = wv & 0xFFFF;
  const int e1 = (int)(wv >> 16);
  const bool v0 = (lane < NSLOT / 2) && (e0 != 0xFFFF);
  const bool v1 = (lane < NSLOT / 2) && (e1 != 0xFFFF);
  const int k = lane >> 1;  // entry j=2*lane and j=2*lane+1 share k = j>>2
  const int p0 = k * Lpairs + e0;
  const int p1 = k * Lpairs + e1;

  unsigned long long m0 = __ballot(v0);
  unsigned long long m1 = __ballot(v1);
  unsigned long long below = ((unsigned long long)1 << lane) - 1ull;
  int c0 = __popcll(m0);
  int cnt = c0 + __popcll(m1);
  int pos0 = __popcll(m0 & below);
  int pos1 = c0 + __popcll(m1 & below);
  if (cnt > 64) cnt = 64;
  if (v0 && pos0 < 64) list[w][pos0] = p0;
  if (v1 && pos1 < 64) list[w][pos1] = p1;
  __syncthreads();

  // out channel c=lane lives at vals offset c' = ((c>>2)&3)*16 + (c>>4)*4 + (c&3)
  const int cp = ((lane >> 2) & 3) * 16 + (lane >> 4) * 4 + (lane & 3);
  float acc = 0.f;
  int j = 0;
  for (; j + 3 < cnt; j += 4) {
    int s0 = list[w][j], s1 = list[w][j + 1], s2 = list[w][j + 2], s3 = list[w][j + 3];
    float q0 = (float)vals[(size_t)s0 * 64 + cp];
    float q1 = (float)vals[(size_t)s1 * 64 + cp];
    float q2 = (float)vals[(size_t)s2 * 64 + cp];
    float q3 = (float)vals[(size_t)s3 * 64 + cp];
    acc += q0; acc += q1; acc += q2; acc += q3;
  }
  for (; j < cnt; ++j) acc += (float)vals[(size_t)list[w][j] * 64 + cp];
  out[(size_t)row * 64 + lane] = acc;
}

// ---- k4: overflow fixup (~500 pairs) ----
__global__ __launch_bounds__(256) void k4_fixup(const __bf16* __restrict__ vals,
                                                const int2* __restrict__ ovf,
                                                const int* __restrict__ ovfcnt,
                                                float* __restrict__ out) {
  int gid = blockIdx.x * 256 + threadIdx.x;
  int i = gid >> 6, lane = gid & 63;
  int n = *ovfcnt;
  if (n > OVFCAP) n = OVFCAP;
  if (i >= n) return;
  int row = ovf[i].x, pid = ovf[i].y;
  const int cp = ((lane >> 2) & 3) * 16 + (lane >> 4) * 4 + (lane & 3);
  atomicAdd(&out[(size_t)row * 64 + lane], (float)vals[(size_t)pid * 64 + cp]);
}

// ---- Fallback: atomic kernel (exotic shapes / tiny ws) ----
template <int ITER>
__global__ __launch_bounds__(256) void spconv_atomic_kernel(
    const float* __restrict__ feat, const float* __restrict__ kern,
    const int* __restrict__ nin, const int* __restrict__ nout,
    float* __restrict__ out, int Lpairs, int blocksPerK) {
  __shared__ __bf16 ldsBT[64 * WPAD];
  const int bk = blockIdx.x / blocksPerK;
  const int chunk = blockIdx.x % blocksPerK;
  const float* kb = kern + bk * 4096;
  for (int idx = threadIdx.x; idx < 4096; idx += 256) {
    int i = idx >> 6, c = idx & 63;
    ldsBT[c * WPAD + i] = (__bf16)kb[idx];
  }
  __syncthreads();
  const int lane = threadIdx.x & 63;
  const int wave = threadIdx.x >> 6;
  const int r = lane & 15, g = lane >> 4;
  bf16x8 bfrag[2][4];
#pragma unroll
  for (int s = 0; s < 2; ++s)
#pragma unroll
    for (int t = 0; t < 4; ++t)
      bfrag[s][t] = *(const bf16x8*)&ldsBT[(t * 16 + r) * WPAD + g * 8 + s * 32];
  const int* ninK = nin + bk * Lpairs;
  const int* noutK = nout + bk * Lpairs;
  const int base0 = chunk * (4 * ITER * 16) + wave * (ITER * 16);
  for (int it = 0; it < ITER; ++it) {
    const int base = base0 + it * 16;
    if (base >= Lpairs) break;
    const int arow = ninK[base + r];
    const float* ap = feat + (size_t)arow * 64 + g * 8;
    f32x4 f0 = *(const f32x4*)(ap);
    f32x4 f1 = *(const f32x4*)(ap + 4);
    f32x4 f2 = *(const f32x4*)(ap + 32);
    f32x4 f3 = *(const f32x4*)(ap + 36);
    bf16x8 a0, a1;
#pragma unroll
    for (int j = 0; j < 4; ++j) {
      a0[j] = (__bf16)f0[j];
      a0[j + 4] = (__bf16)f1[j];
      a1[j] = (__bf16)f2[j];
      a1[j + 4] = (__bf16)f3[j];
    }
    f32x4 acc[4] = {f32x4{0.f, 0.f, 0.f, 0.f}, f32x4{0.f, 0.f, 0.f, 0.f},
                    f32x4{0.f, 0.f, 0.f, 0.f}, f32x4{0.f, 0.f, 0.f, 0.f}};
#pragma unroll
    for (int t = 0; t < 4; ++t) {
      acc[t] = __builtin_amdgcn_mfma_f32_16x16x32_bf16(a0, bfrag[0][t], acc[t], 0, 0, 0);
      acc[t] = __builtin_amdgcn_mfma_f32_16x16x32_bf16(a1, bfrag[1][t], acc[t], 0, 0, 0);
    }
    int orow[4];
#pragma unroll
    for (int reg = 0; reg < 4; ++reg) orow[reg] = noutK[base + g * 4 + reg];
#pragma unroll
    for (int t = 0; t < 4; ++t)
#pragma unroll
      for (int reg = 0; reg < 4; ++reg)
        atomicAdd(out + (size_t)orow[reg] * 64 + t * 16 + r, acc[t][reg]);
  }
}

extern "C" void kernel_launch(void* const* d_in, const int* in_sizes, int n_in,
                              void* d_out, int out_size, void* d_ws, size_t ws_size,
                              hipStream_t stream) {
  const float* feat = (const float*)d_in[0];
  const float* kern = (const float*)d_in[1];
  const int* nin = (const int*)d_in[2];
  const int* nout = (const int*)d_in[3];
  float* out = (float*)d_out;

  const int total = in_sizes[2];        // 27*L pairs
  const int Lpairs = total / KOFF;      // 50000
  const int Nrows = out_size / 64;      // 100000
  const int nElems = Nrows * 64;

  constexpr int ITER = 8;
  const int pairsPerBlock = 4 * ITER * 16;  // 512
  const int blocksPerK = (Lpairs + pairsPerBlock - 1) / pairsPerBlock;

  // ws layout: slots (uint16, 0xFF-init) | ovf | ovfcnt | vals
  const size_t slotsBytes = (size_t)Nrows * NSLOT * 2;
  const size_t ovfOff = (slotsBytes + 255) & ~(size_t)255;
  const size_t cntOff = (ovfOff + (size_t)OVFCAP * 8 + 255) & ~(size_t)255;
  const size_t valsOff = (cntOff + 256 + 255) & ~(size_t)255;
  const size_t needed = valsOff + (size_t)total * 64 * 2;

  const bool shapeOK = (Lpairs <= 65535) && (Nrows <= NIBWORDS * 8) &&
                       (Lpairs % 16 == 0) && (total % KOFF == 0);

  if (shapeOK && ws_size >= needed) {
    unsigned short* slots = (unsigned short*)d_ws;
    int2* ovf = (int2*)((char*)d_ws + ovfOff);
    int* ovfcnt = (int*)((char*)d_ws + cntOff);
    __bf16* vals = (__bf16*)((char*)d_ws + valsOff);
    __bf16* fb = (__bf16*)d_out;  // 12.8 MB scratch inside 25.6 MB out buffer

    hipMemsetAsync(slots, 0xFF, slotsBytes, stream);
    hipMemsetAsync(ovfcnt, 0, 4, stream);

    const int castBlocks = (nElems / 8 + 255) / 256;
    kA_rank_cast<<<KOFF + castBlocks, 256, 0, stream>>>(
        feat, nout, fb, slots, ovf, ovfcnt, Lpairs, nElems);
    k2_gemm<ITER><<<KOFF * blocksPerK, 256, 0, stream>>>(fb, kern, nin, vals,
                                                         Lpairs, blocksPerK);
    k3_reduce<<<(Nrows + 3) / 4, 256, 0, stream>>>(
        vals, (const unsigned int*)slots, out, Nrows, Lpairs);
    k4_fixup<<<OVFCAP * 64 / 256, 256, 0, stream>>>(vals, ovf, ovfcnt, out);
  } else {
    hipMemsetAsync(d_out, 0, (size_t)out_size * sizeof(float), stream);
    spconv_atomic_kernel<ITER><<<KOFF * blocksPerK, 256, 0, stream>>>(
        feat, kern, nin, nout, out, Lpairs, blocksPerK);
  }
}